// Round 1
// baseline (157.754 us; speedup 1.0000x reference)
//
#include <hip/hip_runtime.h>

#define N_NODES 100000
#define DEG 32
#define DIM 256

typedef _Float16 f16x4 __attribute__((ext_vector_type(4)));
typedef float f32x4 __attribute__((ext_vector_type(4)));

// Pre-swizzle W into MFMA B-fragment order, fp16.
// Wswz element layout (f16x4 units): index = (kt*16 + nt)*64 + lane
//   holds W[kt*16 + 4*(lane>>4) + b][nt*16 + (lane&15)] for b=0..3
__global__ void wprep_kernel(const float* __restrict__ W, _Float16* __restrict__ Wswz) {
    int tid = blockIdx.x * blockDim.x + threadIdx.x;  // 0..16383
    int l = tid & 63;
    int frag = tid >> 6;       // kt*16 + nt
    int kt = frag >> 4;
    int nt = frag & 15;
    int krow = kt * 16 + ((l >> 4) << 2);
    int col  = nt * 16 + (l & 15);
    f16x4 v;
#pragma unroll
    for (int b = 0; b < 4; ++b)
        v[b] = (_Float16)W[(size_t)(krow + b) * DIM + col];
    *reinterpret_cast<f16x4*>(Wswz + (size_t)tid * 4) = v;
}

// Block = 256 threads (4 waves). BM = 128 rows, BN = 256 (full width).
// Wave w owns rows [m0 + w*32, +32) as two 16-row strips; K = 256 in 16 steps.
__launch_bounds__(256, 2)
__global__ void agg_kernel(const float* __restrict__ F, const float* __restrict__ Adj,
                           const _Float16* __restrict__ Wswz, float* __restrict__ out) {
    __shared__ float s_amax[128];
    __shared__ float s_amin[128];
    const int m0 = blockIdx.x * 128;
    const int t = threadIdx.x;

    // Per-row adjacency max/min (128 rows, one thread each)
    if (t < 128) {
        int row = m0 + t;
        if (row < N_NODES) {
            const float4* a = reinterpret_cast<const float4*>(Adj + (size_t)row * DEG);
            float mx = -1e30f, mn = 1e30f;
#pragma unroll
            for (int i = 0; i < DEG / 4; ++i) {
                float4 v = a[i];
                mx = fmaxf(mx, fmaxf(fmaxf(v.x, v.y), fmaxf(v.z, v.w)));
                mn = fminf(mn, fminf(fminf(v.x, v.y), fminf(v.z, v.w)));
            }
            s_amax[t] = mx;
            s_amin[t] = mn;
        }
    }
    __syncthreads();

    const int wv = t >> 6;       // wave 0..3
    const int l  = t & 63;
    const int lg = l >> 4;       // lane group 0..3
    const int ll = l & 15;       // lane-in-group

    const int rowA0 = m0 + wv * 32 + ll;       // strip 0 A-row for this lane
    const int rowA1 = rowA0 + 16;              // strip 1
    const int ra0 = rowA0 < N_NODES ? rowA0 : (N_NODES - 1);
    const int ra1 = rowA1 < N_NODES ? rowA1 : (N_NODES - 1);
    const float4* A0 = reinterpret_cast<const float4*>(F + (size_t)ra0 * DIM) + lg;
    const float4* A1 = reinterpret_cast<const float4*>(F + (size_t)ra1 * DIM) + lg;

    f32x4 acc[2][16];
#pragma unroll
    for (int s = 0; s < 2; ++s)
#pragma unroll
        for (int nt = 0; nt < 16; ++nt)
            acc[s][nt] = (f32x4){0.f, 0.f, 0.f, 0.f};

    const f16x4* B = reinterpret_cast<const f16x4*>(Wswz);

#pragma unroll 4
    for (int kt = 0; kt < 16; ++kt) {
        float4 ar0 = A0[kt * 4];   // k = kt*16 + lg*4 .. +3
        float4 ar1 = A1[kt * 4];
        f16x4 a0, a1;
        a0[0] = (_Float16)ar0.x; a0[1] = (_Float16)ar0.y;
        a0[2] = (_Float16)ar0.z; a0[3] = (_Float16)ar0.w;
        a1[0] = (_Float16)ar1.x; a1[1] = (_Float16)ar1.y;
        a1[2] = (_Float16)ar1.z; a1[3] = (_Float16)ar1.w;
        const f16x4* Bk = B + (size_t)(kt * 16) * 64 + l;
#pragma unroll
        for (int nt = 0; nt < 16; ++nt) {
            f16x4 b = Bk[nt * 64];
            acc[0][nt] = __builtin_amdgcn_mfma_f32_16x16x16f16(a0, b, acc[0][nt], 0, 0, 0);
            acc[1][nt] = __builtin_amdgcn_mfma_f32_16x16x16f16(a1, b, acc[1][nt], 0, 0, 0);
        }
    }

    // Epilogue: out = max(amax*p, amin*p, 0)
#pragma unroll
    for (int s = 0; s < 2; ++s) {
        const int rbase = wv * 32 + s * 16 + 4 * lg;    // local row base in block
#pragma unroll
        for (int r = 0; r < 4; ++r) {
            const int lr = rbase + r;
            const int row = m0 + lr;
            if (row < N_NODES) {
                const float amax = s_amax[lr];
                const float amin = s_amin[lr];
                float* orow = out + (size_t)row * DIM + ll;
#pragma unroll
                for (int nt = 0; nt < 16; ++nt) {
                    float p = acc[s][nt][r];
                    float v = fmaxf(fmaxf(amax * p, amin * p), 0.0f);
                    orow[nt * 16] = v;
                }
            }
        }
    }
}

extern "C" void kernel_launch(void* const* d_in, const int* in_sizes, int n_in,
                              void* d_out, int out_size, void* d_ws, size_t ws_size,
                              hipStream_t stream) {
    const float* F   = (const float*)d_in[0];
    const float* Adj = (const float*)d_in[1];
    const float* W   = (const float*)d_in[2];
    float* out = (float*)d_out;
    _Float16* Wswz = (_Float16*)d_ws;   // 256*256*2 = 128 KB

    hipLaunchKernelGGL(wprep_kernel, dim3(64), dim3(256), 0, stream, W, Wswz);
    const int nblk = (N_NODES + 127) / 128;   // 782
    hipLaunchKernelGGL(agg_kernel, dim3(nblk), dim3(256), 0, stream, F, Adj, Wswz, out);
}

// Round 2
// 79.246 us; speedup vs baseline: 1.9907x; 1.9907x over previous
//
#include <hip/hip_runtime.h>

#define N_NODES 100000
#define DEG 32
#define DIM 256

typedef _Float16 f16x4 __attribute__((ext_vector_type(4)));
typedef _Float16 f16x8 __attribute__((ext_vector_type(8)));
typedef float f32x4 __attribute__((ext_vector_type(4)));

// Wswz layout: f16x8 units, idx = (kt*8 + np)*64 + lane.
// Unit element j: nt = 2*np + (j>>2), b = j&3, holds
//   W[kt*16 + 4*(lane>>4) + b][nt*16 + (lane&15)]
// i.e. two adjacent-nt B-fragments packed per 16B lane load.
__global__ void wprep_kernel(const float* __restrict__ W, _Float16* __restrict__ Wswz) {
    int tid = blockIdx.x * blockDim.x + threadIdx.x;  // 0..8191
    int l = tid & 63;
    int unit = tid >> 6;           // 0..127
    int kt = unit >> 3;
    int np = unit & 7;
    int krow = kt * 16 + ((l >> 4) << 2);
    int col0 = (np * 2) * 16 + (l & 15);
    f16x8 v;
#pragma unroll
    for (int j = 0; j < 8; ++j) {
        int b = j & 3;
        int ntoff = (j >> 2) * 16;
        v[j] = (_Float16)W[(size_t)(krow + b) * DIM + col0 + ntoff];
    }
    *reinterpret_cast<f16x8*>(Wswz + (size_t)tid * 8) = v;
}

// Block = 256 threads (4 waves), BM = 64 rows. Each wave: 16 rows x 256 cols.
// acc = 16 x f32x4 = 64 VGPR. K = 256 in 16 steps of 16.
__launch_bounds__(256, 4)
__global__ void agg_kernel(const float* __restrict__ F, const float* __restrict__ Adj,
                           const _Float16* __restrict__ Wswz, float* __restrict__ out) {
    __shared__ float s_amax[64];
    __shared__ float s_amin[64];
    const int m0 = blockIdx.x * 64;
    const int t = threadIdx.x;

    if (t < 64) {
        int row = m0 + t;
        int rr = row < N_NODES ? row : (N_NODES - 1);
        const float4* a = reinterpret_cast<const float4*>(Adj + (size_t)rr * DEG);
        float mx = -1e30f, mn = 1e30f;
#pragma unroll
        for (int i = 0; i < DEG / 4; ++i) {
            float4 v = a[i];
            mx = fmaxf(mx, fmaxf(fmaxf(v.x, v.y), fmaxf(v.z, v.w)));
            mn = fminf(mn, fminf(fminf(v.x, v.y), fminf(v.z, v.w)));
        }
        s_amax[t] = mx;
        s_amin[t] = mn;
    }
    __syncthreads();

    const int wv = t >> 6;
    const int l  = t & 63;
    const int lg = l >> 4;
    const int ll = l & 15;

    const int rowA = m0 + wv * 16 + ll;
    const int ra = rowA < N_NODES ? rowA : (N_NODES - 1);
    const float4* A = reinterpret_cast<const float4*>(F + (size_t)ra * DIM) + lg;

    f32x4 acc[16];
#pragma unroll
    for (int nt = 0; nt < 16; ++nt)
        acc[nt] = (f32x4){0.f, 0.f, 0.f, 0.f};

    const f16x8* B = reinterpret_cast<const f16x8*>(Wswz) + l;

    float4 a_nxt = A[0];
#pragma unroll 4
    for (int kt = 0; kt < 16; ++kt) {
        float4 ac = a_nxt;
        if (kt < 15) a_nxt = A[(kt + 1) * 4];
        f16x4 af;
        af[0] = (_Float16)ac.x; af[1] = (_Float16)ac.y;
        af[2] = (_Float16)ac.z; af[3] = (_Float16)ac.w;
        const f16x8* Bk = B + (size_t)kt * 8 * 64;
#pragma unroll
        for (int np = 0; np < 8; ++np) {
            f16x8 b = Bk[np * 64];
            f16x4 blo = __builtin_shufflevector(b, b, 0, 1, 2, 3);
            f16x4 bhi = __builtin_shufflevector(b, b, 4, 5, 6, 7);
            acc[2 * np]     = __builtin_amdgcn_mfma_f32_16x16x16f16(af, blo, acc[2 * np], 0, 0, 0);
            acc[2 * np + 1] = __builtin_amdgcn_mfma_f32_16x16x16f16(af, bhi, acc[2 * np + 1], 0, 0, 0);
        }
    }

    // Epilogue: out = max(amax*p, amin*p, 0), nontemporal (write-once stream)
    const int rbase = wv * 16 + 4 * lg;
#pragma unroll
    for (int r = 0; r < 4; ++r) {
        const int lr = rbase + r;
        const int row = m0 + lr;
        if (row < N_NODES) {
            const float amax = s_amax[lr];
            const float amin = s_amin[lr];
            float* orow = out + (size_t)row * DIM + ll;
#pragma unroll
            for (int nt = 0; nt < 16; ++nt) {
                float p = acc[nt][r];
                float v = fmaxf(fmaxf(amax * p, amin * p), 0.0f);
                __builtin_nontemporal_store(v, orow + nt * 16);
            }
        }
    }
}

extern "C" void kernel_launch(void* const* d_in, const int* in_sizes, int n_in,
                              void* d_out, int out_size, void* d_ws, size_t ws_size,
                              hipStream_t stream) {
    const float* F   = (const float*)d_in[0];
    const float* Adj = (const float*)d_in[1];
    const float* W   = (const float*)d_in[2];
    float* out = (float*)d_out;
    _Float16* Wswz = (_Float16*)d_ws;   // 256*256*2 = 128 KB

    hipLaunchKernelGGL(wprep_kernel, dim3(32), dim3(256), 0, stream, W, Wswz);
    const int nblk = (N_NODES + 63) / 64;   // 1563
    hipLaunchKernelGGL(agg_kernel, dim3(nblk), dim3(256), 0, stream, F, Adj, Wswz, out);
}

// Round 3
// 76.486 us; speedup vs baseline: 2.0625x; 1.0361x over previous
//
#include <hip/hip_runtime.h>

#define N_NODES 100000
#define DEG 32
#define DIM 256

typedef _Float16 f16x8 __attribute__((ext_vector_type(8)));
typedef float f32x4 __attribute__((ext_vector_type(4)));

// Wswz layout: f16x8 units, idx = (kt*16 + nt)*64 + lane, kt in [0,8), nt in [0,16).
// Unit element j holds W[kt*32 + 4*(lane>>4) + (j&3) + 16*(j>>2)][nt*16 + (lane&15)]
// (B fragment for mfma_f32_16x16x32_f16; A uses the identical (lane,j)->k map, so
//  any k-permutation error cancels in the contraction.)
__global__ void wprep_kernel(const float* __restrict__ W, _Float16* __restrict__ Wswz) {
    int tid = blockIdx.x * blockDim.x + threadIdx.x;  // 0..8191
    int l = tid & 63;
    int frag = tid >> 6;        // kt*16 + nt
    int kt = frag >> 4;
    int nt = frag & 15;
    int col = nt * 16 + (l & 15);
    int kbase = kt * 32 + ((l >> 4) << 2);
    f16x8 v;
#pragma unroll
    for (int j = 0; j < 8; ++j) {
        int k = kbase + (j & 3) + ((j >> 2) << 4);
        v[j] = (_Float16)W[(size_t)k * DIM + col];
    }
    *reinterpret_cast<f16x8*>(Wswz + (size_t)tid * 8) = v;
}

// Block = 256 threads (4 waves). Tile = 64 rows x 128 cols (nh selects col half).
// Each wave: 16 rows x 128 cols, acc = 8 x f32x4 = 32 regs. K = 256 in 8 steps of 32.
__launch_bounds__(256, 4)
__global__ void agg_kernel(const float* __restrict__ F, const float* __restrict__ Adj,
                           const _Float16* __restrict__ Wswz, float* __restrict__ out) {
    __shared__ float s_amax[64];
    __shared__ float s_amin[64];
    const int bx = blockIdx.x;
    const int tile = bx >> 1;
    const int nh = bx & 1;
    const int m0 = tile * 64;
    const int n0 = nh * 128;
    const int t = threadIdx.x;

    if (t < 64) {
        int row = m0 + t;
        int rr = row < N_NODES ? row : (N_NODES - 1);
        const float4* a = reinterpret_cast<const float4*>(Adj + (size_t)rr * DEG);
        float mx = -1e30f, mn = 1e30f;
#pragma unroll
        for (int i = 0; i < DEG / 4; ++i) {
            float4 v = a[i];
            mx = fmaxf(mx, fmaxf(fmaxf(v.x, v.y), fmaxf(v.z, v.w)));
            mn = fminf(mn, fminf(fminf(v.x, v.y), fminf(v.z, v.w)));
        }
        s_amax[t] = mx;
        s_amin[t] = mn;
    }
    __syncthreads();

    const int wv = t >> 6;
    const int l  = t & 63;
    const int lg = l >> 4;
    const int ll = l & 15;

    const int rowA = m0 + wv * 16 + ll;
    const int ra = rowA < N_NODES ? rowA : (N_NODES - 1);
    const float* Arow = F + (size_t)ra * DIM + 4 * lg;

    f32x4 acc[8];
#pragma unroll
    for (int np = 0; np < 8; ++np)
        acc[np] = (f32x4){0.f, 0.f, 0.f, 0.f};

    // B base for this col-half: fragments nt = nh*8 + np
    const f16x8* B = reinterpret_cast<const f16x8*>(Wswz) + (size_t)(nh * 8) * 64 + l;

    // Distance-2 A prefetch pipeline
    float4 c_lo = *reinterpret_cast<const float4*>(Arow + 0);
    float4 c_hi = *reinterpret_cast<const float4*>(Arow + 16);
    float4 n_lo = *reinterpret_cast<const float4*>(Arow + 32);
    float4 n_hi = *reinterpret_cast<const float4*>(Arow + 48);

#pragma unroll
    for (int kt = 0; kt < 8; ++kt) {
        float4 p_lo, p_hi;
        if (kt < 6) {
            p_lo = *reinterpret_cast<const float4*>(Arow + (kt + 2) * 32);
            p_hi = *reinterpret_cast<const float4*>(Arow + (kt + 2) * 32 + 16);
        }
        f16x8 af;
        af[0] = (_Float16)c_lo.x; af[1] = (_Float16)c_lo.y;
        af[2] = (_Float16)c_lo.z; af[3] = (_Float16)c_lo.w;
        af[4] = (_Float16)c_hi.x; af[5] = (_Float16)c_hi.y;
        af[6] = (_Float16)c_hi.z; af[7] = (_Float16)c_hi.w;
        const f16x8* Bk = B + (size_t)kt * 16 * 64;
#pragma unroll
        for (int np = 0; np < 8; ++np) {
            f16x8 b = Bk[np * 64];
            acc[np] = __builtin_amdgcn_mfma_f32_16x16x32_f16(af, b, acc[np], 0, 0, 0);
        }
        c_lo = n_lo; c_hi = n_hi;
        n_lo = p_lo; n_hi = p_hi;
    }

    // Epilogue: out = max(amax*p, amin*p, 0)
    const int rbase = wv * 16 + 4 * lg;
#pragma unroll
    for (int r = 0; r < 4; ++r) {
        const int lr = rbase + r;
        const int row = m0 + lr;
        if (row < N_NODES) {
            const float amax = s_amax[lr];
            const float amin = s_amin[lr];
            float* orow = out + (size_t)row * DIM + n0 + ll;
#pragma unroll
            for (int np = 0; np < 8; ++np) {
                float p = acc[np][r];
                orow[np * 16] = fmaxf(fmaxf(amax * p, amin * p), 0.0f);
            }
        }
    }
}

extern "C" void kernel_launch(void* const* d_in, const int* in_sizes, int n_in,
                              void* d_out, int out_size, void* d_ws, size_t ws_size,
                              hipStream_t stream) {
    const float* F   = (const float*)d_in[0];
    const float* Adj = (const float*)d_in[1];
    const float* W   = (const float*)d_in[2];
    float* out = (float*)d_out;
    _Float16* Wswz = (_Float16*)d_ws;   // 256*256*2 = 128 KB

    hipLaunchKernelGGL(wprep_kernel, dim3(32), dim3(256), 0, stream, W, Wswz);
    const int nblk = ((N_NODES + 63) / 64) * 2;   // 3126
    hipLaunchKernelGGL(agg_kernel, dim3(nblk), dim3(256), 0, stream, F, Adj, Wswz, out);
}

// Round 4
// 76.062 us; speedup vs baseline: 2.0740x; 1.0056x over previous
//
#include <hip/hip_runtime.h>

#define N_NODES 100000
#define DEG 32
#define DIM 256

typedef _Float16 f16x8 __attribute__((ext_vector_type(8)));
typedef float f32x4 __attribute__((ext_vector_type(4)));

// Wswz layout: f16x8 units, idx = (kt*16 + nt)*64 + lane, kt in [0,8), nt in [0,16).
// Unit element j holds W[kt*32 + 4*(lane>>4) + (j&3) + 16*(j>>2)][nt*16 + (lane&15)]
// (B fragment for mfma_f32_16x16x32_f16; A uses the identical (lane,j)->k map, so
//  any k-permutation error cancels in the contraction.)
__global__ void wprep_kernel(const float* __restrict__ W, _Float16* __restrict__ Wswz) {
    int tid = blockIdx.x * blockDim.x + threadIdx.x;  // 0..8191
    int l = tid & 63;
    int frag = tid >> 6;        // kt*16 + nt
    int kt = frag >> 4;
    int nt = frag & 15;
    int col = nt * 16 + (l & 15);
    int kbase = kt * 32 + ((l >> 4) << 2);
    f16x8 v;
#pragma unroll
    for (int j = 0; j < 8; ++j) {
        int k = kbase + (j & 3) + ((j >> 2) << 4);
        v[j] = (_Float16)W[(size_t)k * DIM + col];
    }
    *reinterpret_cast<f16x8*>(Wswz + (size_t)tid * 8) = v;
}

// Block = 256 threads (4 waves). Tile = 64 rows x 128 cols (nh = col half).
// Each wave: 16 rows x 128 cols, acc = 8 x f32x4 = 32 regs.
// A is loaded ENTIRELY upfront (16 x dwordx4 burst per lane), converted to f16;
// the K-loop is then a clean B-load -> MFMA stream with nothing else in the
// vmem queue, so the compiler can pipeline B loads across kt.
__launch_bounds__(256, 4)
__global__ void agg_kernel(const float* __restrict__ F, const float* __restrict__ Adj,
                           const _Float16* __restrict__ Wswz, float* __restrict__ out) {
    __shared__ float s_amax[64];
    __shared__ float s_amin[64];
    const int bx = blockIdx.x;
    const int tile = bx >> 1;
    const int nh = bx & 1;
    const int m0 = tile * 64;
    const int n0 = nh * 128;
    const int t = threadIdx.x;

    if (t < 64) {
        int row = m0 + t;
        int rr = row < N_NODES ? row : (N_NODES - 1);
        const float4* a = reinterpret_cast<const float4*>(Adj + (size_t)rr * DEG);
        float mx = -1e30f, mn = 1e30f;
#pragma unroll
        for (int i = 0; i < DEG / 4; ++i) {
            float4 v = a[i];
            mx = fmaxf(mx, fmaxf(fmaxf(v.x, v.y), fmaxf(v.z, v.w)));
            mn = fminf(mn, fminf(fminf(v.x, v.y), fminf(v.z, v.w)));
        }
        s_amax[t] = mx;
        s_amin[t] = mn;
    }
    __syncthreads();

    const int wv = t >> 6;
    const int l  = t & 63;
    const int lg = l >> 4;
    const int ll = l & 15;

    const int rowA = m0 + wv * 16 + ll;
    const int ra = rowA < N_NODES ? rowA : (N_NODES - 1);
    const float4* Af4 = reinterpret_cast<const float4*>(F + (size_t)ra * DIM) + lg;

    // ---- upfront A burst: 16 independent 16B loads per lane ----
    float4 alo[8], ahi[8];
#pragma unroll
    for (int kt = 0; kt < 8; ++kt) {
        alo[kt] = Af4[kt * 8];       // k = kt*32 + 4*lg .. +3
        ahi[kt] = Af4[kt * 8 + 4];   // k = kt*32 + 16 + 4*lg .. +3
    }
    // convert to f16 fragments as the loads retire (descending vmcnt waits)
    f16x8 a16[8];
#pragma unroll
    for (int kt = 0; kt < 8; ++kt) {
        f16x8 af;
        af[0] = (_Float16)alo[kt].x; af[1] = (_Float16)alo[kt].y;
        af[2] = (_Float16)alo[kt].z; af[3] = (_Float16)alo[kt].w;
        af[4] = (_Float16)ahi[kt].x; af[5] = (_Float16)ahi[kt].y;
        af[6] = (_Float16)ahi[kt].z; af[7] = (_Float16)ahi[kt].w;
        a16[kt] = af;
    }

    f32x4 acc[8];
#pragma unroll
    for (int np = 0; np < 8; ++np)
        acc[np] = (f32x4){0.f, 0.f, 0.f, 0.f};

    const f16x8* B = reinterpret_cast<const f16x8*>(Wswz) + (size_t)(nh * 8) * 64 + l;

    // ---- pure B-load -> MFMA stream ----
#pragma unroll
    for (int kt = 0; kt < 8; ++kt) {
        const f16x8* Bk = B + (size_t)kt * 16 * 64;
#pragma unroll
        for (int np = 0; np < 8; ++np) {
            f16x8 b = Bk[np * 64];
            acc[np] = __builtin_amdgcn_mfma_f32_16x16x32_f16(a16[kt], b, acc[np], 0, 0, 0);
        }
    }

    // Epilogue: out = max(amax*p, amin*p, 0)
    const int rbase = wv * 16 + 4 * lg;
#pragma unroll
    for (int r = 0; r < 4; ++r) {
        const int lr = rbase + r;
        const int row = m0 + lr;
        if (row < N_NODES) {
            const float amax = s_amax[lr];
            const float amin = s_amin[lr];
            float* orow = out + (size_t)row * DIM + n0 + ll;
#pragma unroll
            for (int np = 0; np < 8; ++np) {
                float p = acc[np][r];
                orow[np * 16] = fmaxf(fmaxf(amax * p, amin * p), 0.0f);
            }
        }
    }
}

extern "C" void kernel_launch(void* const* d_in, const int* in_sizes, int n_in,
                              void* d_out, int out_size, void* d_ws, size_t ws_size,
                              hipStream_t stream) {
    const float* F   = (const float*)d_in[0];
    const float* Adj = (const float*)d_in[1];
    const float* W   = (const float*)d_in[2];
    float* out = (float*)d_out;
    _Float16* Wswz = (_Float16*)d_ws;   // 256*256*2 = 128 KB

    hipLaunchKernelGGL(wprep_kernel, dim3(32), dim3(256), 0, stream, W, Wswz);
    const int nblk = ((N_NODES + 63) / 64) * 2;   // 3126
    hipLaunchKernelGGL(agg_kernel, dim3(nblk), dim3(256), 0, stream, F, Adj, Wswz, out);
}

// Round 5
// 64.377 us; speedup vs baseline: 2.4505x; 1.1815x over previous
//
#include <hip/hip_runtime.h>

#define N_NODES 100000
#define DEG 32
#define DIM 256

typedef _Float16 f16x8 __attribute__((ext_vector_type(8)));
typedef float f32x4 __attribute__((ext_vector_type(4)));

// Wswz layout: f16x8 units, idx = (kt*16 + nt)*64 + lane, kt in [0,8), nt in [0,16).
// Unit element j holds W[kt*32 + 4*(lane>>4) + (j&3) + 16*(j>>2)][nt*16 + (lane&15)]
// (B fragment for mfma_f32_16x16x32_f16; A uses the identical (lane,j)->k map, so
//  any k-permutation error cancels in the contraction.)
__global__ void wprep_kernel(const float* __restrict__ W, _Float16* __restrict__ Wswz) {
    int tid = blockIdx.x * blockDim.x + threadIdx.x;  // 0..8191
    int l = tid & 63;
    int frag = tid >> 6;        // kt*16 + nt
    int kt = frag >> 4;
    int nt = frag & 15;
    int col = nt * 16 + (l & 15);
    int kbase = kt * 32 + ((l >> 4) << 2);
    f16x8 v;
#pragma unroll
    for (int j = 0; j < 8; ++j) {
        int k = kbase + (j & 3) + ((j >> 2) << 4);
        v[j] = (_Float16)W[(size_t)k * DIM + col];
    }
    *reinterpret_cast<f16x8*>(Wswz + (size_t)tid * 8) = v;
}

// Block = 512 threads (8 waves). Tile = 128 rows x 128 cols (nh = col half).
// B col-half staged in LDS (64 KB); inner loop is ds_read_b128 -> MFMA (lgkmcnt
// pipelined by compiler), so the only global loads are the upfront A burst.
// Each wave: 16 rows x 128 cols, acc = 8 x f32x4 = 32 regs.
__launch_bounds__(512, 4)
__global__ void agg_kernel(const float* __restrict__ F, const float* __restrict__ Adj,
                           const _Float16* __restrict__ Wswz, float* __restrict__ out) {
    __shared__ _Float16 sB[8 * 8 * 64 * 8];   // 64 KB: fragment (kt,np) at ((kt*8+np)*64+l)*8
    __shared__ float s_amax[128];
    __shared__ float s_amin[128];

    const int bx = blockIdx.x;
    const int tile = bx >> 1;
    const int nh = bx & 1;
    const int m0 = tile * 128;
    const int n0 = nh * 128;
    const int t = threadIdx.x;
    const int wv = t >> 6;     // wave 0..7
    const int l  = t & 63;
    const int lg = l >> 4;
    const int ll = l & 15;

    // ---- adjacency max/min for this block's 128 rows ----
    if (t < 128) {
        int row = m0 + t;
        int rr = row < N_NODES ? row : (N_NODES - 1);
        const float4* a = reinterpret_cast<const float4*>(Adj + (size_t)rr * DEG);
        float mx = -1e30f, mn = 1e30f;
#pragma unroll
        for (int i = 0; i < DEG / 4; ++i) {
            float4 v = a[i];
            mx = fmaxf(mx, fmaxf(fmaxf(v.x, v.y), fmaxf(v.z, v.w)));
            mn = fminf(mn, fminf(fminf(v.x, v.y), fminf(v.z, v.w)));
        }
        s_amax[t] = mx;
        s_amin[t] = mn;
    }

    // ---- issue A burst early (HBM latency hides under B staging) ----
    const int rowA = m0 + wv * 16 + ll;
    const int ra = rowA < N_NODES ? rowA : (N_NODES - 1);
    const float4* Af4 = reinterpret_cast<const float4*>(F + (size_t)ra * DIM) + lg;
    float4 alo[8], ahi[8];
#pragma unroll
    for (int kt = 0; kt < 8; ++kt) {
        alo[kt] = Af4[kt * 8];       // k = kt*32 + 4*lg .. +3
        ahi[kt] = Af4[kt * 8 + 4];   // k = kt*32 + 16 + 4*lg .. +3
    }

    // ---- stage B col-half into LDS: 64 chunks of 1 KB, wave wv takes 8 ----
#pragma unroll
    for (int i = 0; i < 8; ++i) {
        int c = wv * 8 + i;                       // c = kt*8 + np
        int kt = c >> 3, np = c & 7;
        int srcfrag = kt * 16 + nh * 8 + np;
        f16x8 v = *reinterpret_cast<const f16x8*>(Wswz + ((size_t)srcfrag * 64 + l) * 8);
        *reinterpret_cast<f16x8*>(&sB[((size_t)c * 64 + l) * 8]) = v;
    }

    // ---- convert A to f16 fragments (pre-barrier; overlaps others' staging) ----
    f16x8 a16[8];
#pragma unroll
    for (int kt = 0; kt < 8; ++kt) {
        f16x8 af;
        af[0] = (_Float16)alo[kt].x; af[1] = (_Float16)alo[kt].y;
        af[2] = (_Float16)alo[kt].z; af[3] = (_Float16)alo[kt].w;
        af[4] = (_Float16)ahi[kt].x; af[5] = (_Float16)ahi[kt].y;
        af[6] = (_Float16)ahi[kt].z; af[7] = (_Float16)ahi[kt].w;
        a16[kt] = af;
    }

    __syncthreads();

    f32x4 acc[8];
#pragma unroll
    for (int np = 0; np < 8; ++np)
        acc[np] = (f32x4){0.f, 0.f, 0.f, 0.f};

    // ---- pure ds_read -> MFMA stream ----
    const f16x8* Bl = reinterpret_cast<const f16x8*>(sB) + l;
#pragma unroll
    for (int kt = 0; kt < 8; ++kt) {
#pragma unroll
        for (int np = 0; np < 8; ++np) {
            f16x8 b = Bl[(kt * 8 + np) * 64];
            acc[np] = __builtin_amdgcn_mfma_f32_16x16x32_f16(a16[kt], b, acc[np], 0, 0, 0);
        }
    }

    // ---- epilogue: out = max(amax*p, amin*p, 0) ----
    const int rbase = wv * 16 + 4 * lg;
#pragma unroll
    for (int r = 0; r < 4; ++r) {
        const int lr = rbase + r;
        const int row = m0 + lr;
        if (row < N_NODES) {
            const float amax = s_amax[lr];
            const float amin = s_amin[lr];
            float* orow = out + (size_t)row * DIM + n0 + ll;
#pragma unroll
            for (int np = 0; np < 8; ++np) {
                float p = acc[np][r];
                orow[np * 16] = fmaxf(fmaxf(amax * p, amin * p), 0.0f);
            }
        }
    }
}

extern "C" void kernel_launch(void* const* d_in, const int* in_sizes, int n_in,
                              void* d_out, int out_size, void* d_ws, size_t ws_size,
                              hipStream_t stream) {
    const float* F   = (const float*)d_in[0];
    const float* Adj = (const float*)d_in[1];
    const float* W   = (const float*)d_in[2];
    float* out = (float*)d_out;
    _Float16* Wswz = (_Float16*)d_ws;   // 256*256*2 = 128 KB

    hipLaunchKernelGGL(wprep_kernel, dim3(32), dim3(256), 0, stream, W, Wswz);
    const int nblk = ((N_NODES + 127) / 128) * 2;   // 1564
    hipLaunchKernelGGL(agg_kernel, dim3(nblk), dim3(512), 0, stream, F, Adj, Wswz, out);
}